// Round 7
// baseline (1900.175 us; speedup 1.0000x reference)
//
#include <hip/hip_runtime.h>

#define NEG_ (-1e9f)

__constant__ int d_pat[24] = {0,1,2,1,3,4,2,5,6,7,0,2,1,4,3,5,0,6,2,7,1,3,5,4};

// Faithful np emulation: C = log(ss) fp32; cs = [0, cumsum(C)] sequential fp32.
__global__ void k_cs(const float* __restrict__ ss, float* __restrict__ cs){
  int row = threadIdx.x;          // b*8+s, 0..255 (single block of 256)
  const float* sp = ss + row*256;
  float* cp = cs + row*257;
  cp[0] = 0.0f;
  float acc = 0.0f;
  for(int i=0;i<256;i++){
    acc = acc + logf(sp[i]);      // sequential fp32, matches np.cumsum
    cp[i+1] = acc;
  }
}

// QT[p,k,j] = Q[p,j,k]  (pure copy, no rounding)
__global__ void k_tq(const float* __restrict__ Q, float* __restrict__ QT){
  __shared__ float tile[32][33];
  int p = blockIdx.z;
  int j0 = blockIdx.x*32, k0 = blockIdx.y*32;
  int tx = threadIdx.x, ty = threadIdx.y;
  for(int r=ty; r<32; r+=8){
    int j=j0+r, k=k0+tx;
    if(j<257 && k<257) tile[r][tx] = Q[p*66049 + j*257 + k];
  }
  __syncthreads();
  for(int r=ty; r<32; r+=8){
    int k=k0+r, j=j0+tx;
    if(k<257 && j<257) QT[p*66049 + k*257 + j] = tile[tx][r];
  }
}

// Normalized-scan recursions, faithful fp32 op order vs the reference.
// blocks 0..31: forward (alpha), 32..63: backward (beta).
__global__ __launch_bounds__(320) void k_recur(
    const float* __restrict__ Q, const float* __restrict__ QT,
    const float* __restrict__ cs, const int* __restrict__ ls,
    float* __restrict__ alpha, float* __restrict__ beta){
  int blk = blockIdx.x;
  bool fwd = (blk < 32);
  int b = fwd ? blk : blk - 32;
  int tid = threadIdx.x;
  int wv = tid >> 6, lane = tid & 63;
  __shared__ float la[257];        // carried normalized state
  __shared__ float csh[2056];
  __shared__ float wred[5], wred2[5];
  for(int i=tid;i<2056;i+=320) csh[i] = cs[b*2056 + i];
  float ln = 0.0f;                 // n0 = logsumexp(a0) = 0 exactly (exp(-1e9)=0)
  if(fwd){
    if(tid<257){
      float v = (tid==0) ? 0.0f : NEG_;
      la[tid] = v;
      alpha[(b*25)*257 + tid] = v; // a0n + n0 = a0
    }
  } else {
    int lsb = ls[b];
    if(tid<257){
      float v = (tid==lsb) ? 0.0f : NEG_;
      la[tid] = v;
      beta[(b*25+24)*257 + tid] = v;
    }
  }
  __syncthreads();
  for(int step=0; step<24; step++){
    int l = fwd ? step : 23 - step;
    int p = d_pat[l];
    const float* cp = csh + p*257;
    const float* Mx = (fwd ? Q : QT) + p*66049;  // both coalesced per-lane
    // per-thread LSE over the 257 "other" states (online; max exact, sum ~1e-7)
    float m = -3.0e38f, s = 0.0f;
    if(tid<257){
      int me = tid;
      float cme = cp[me];
      for(int o=0;o<257;o++){
        float q = Mx[o*257 + me];
        float w;
        if(fwd) w = (o < me) ? ((cme - cp[o]) + q) : NEG_;  // W_neg = -1e9 exactly
        else    w = (me < o) ? ((cp[o] - cme) + q) : NEG_;
        float x = w + la[o];
        if(x <= m) s += __expf(x - m);
        else { s = s*__expf(m - x) + 1.0f; m = x; }
      }
    }
    float anew = (tid<257) ? (logf(s) + m) : -3.0e38f;   // log(sum)+amax as in scipy
    // block LSE over anew -> n
    float mm = anew;
    for(int off=32; off; off>>=1) mm = fmaxf(mm, __shfl_xor(mm, off));
    if(lane==0) wred[wv] = mm;
    __syncthreads();                               // also guards la reads done
    float gmax = fmaxf(fmaxf(fmaxf(wred[0],wred[1]),fmaxf(wred[2],wred[3])),wred[4]);
    float e = (tid<257) ? __expf(anew - gmax) : 0.0f;
    for(int off=32; off; off>>=1) e += __shfl_xor(e, off);
    if(lane==0) wred2[wv] = e;
    __syncthreads();
    float ssum = ((wred2[0]+wred2[1]) + (wred2[2]+wred2[3])) + wred2[4];
    float l2 = logf(ssum) + gmax;
    float nn = ln + l2;            // n = ln + logsumexp(a)
    float d  = ln - nn;            // (ln - n)
    if(tid<257){
      float lan = anew + d;        // a = a + (ln - n)   (carry)
      la[tid] = lan;
      float st = lan + nn;         // output a + n
      if(fwd) alpha[(b*25 + l+1)*257 + tid] = st;
      else    beta [(b*25 + l  )*257 + tid] = st;
    }
    ln = nn;
    __syncthreads();
  }
}

__global__ void k_M(const float* __restrict__ alpha, const int* __restrict__ ls,
                    float* __restrict__ Mws, float* __restrict__ outM){
  int b = threadIdx.x;
  if(b<32){
    float v = alpha[(b*25+24)*257 + ls[b]];
    Mws[b] = v; outM[b] = v;
  }
}

__global__ void k_ll(const float* __restrict__ alpha, const float* __restrict__ beta,
                     float* __restrict__ out){
  int i = blockIdx.x*256 + threadIdx.x;
  if(i < 32*25*257) out[i] = alpha[i] + beta[i];
}

// one block per (b,l): t (coalesced store), p (online LSE), diagonal traces.
__global__ __launch_bounds__(320) void k_phase3(
    const float* __restrict__ Q, const float* __restrict__ cs,
    const float* __restrict__ alpha, const float* __restrict__ beta,
    const float* __restrict__ Mws,
    float* __restrict__ t_out, float* __restrict__ p_out, float* __restrict__ Lf){
  int bl = blockIdx.x;
  int b = bl/24, l = bl - b*24;
  int pat = d_pat[l];
  int tid = threadIdx.x;
  int wv = tid>>6, lane = tid&63;
  __shared__ float ash[257], bsh[257], cshl[257];
  __shared__ float trd[29];
  __shared__ float wm_[5], ws_[5];
  if(tid<29) trd[tid] = 0.0f;
  for(int i=tid;i<257;i+=320){
    ash[i]  = alpha[(b*25 + l)*257 + i];
    bsh[i]  = beta [(b*25 + l+1)*257 + i];
    cshl[i] = cs[(b*8 + pat)*257 + i];
  }
  float M = Mws[b];
  __syncthreads();
  const float* Qp = Q + pat*66049;
  float* tp = t_out + (long)bl*66049;
  float pm = -3.0e38f, ps = 0.0f;
  if(tid<257){
    int k = tid;
    float bk = bsh[k], ck = cshl[k];
    for(int j=0;j<257;j++){
      float q  = Qp[j*257 + k];
      float w  = (j<k) ? ((ck - cshl[j]) + q) : NEG_;   // fp32(-1e9+q) = -1e9
      float t1 = ash[j] + bk;        // (alpha + beta)
      float t2 = t1 + w;             // ... + W
      float tv = t2 - M;             // ... - M   (left-assoc like numpy)
      tp[j*257 + k] = tv;
      float v2 = tv + w;             // t + W for p
      if(v2 <= pm) ps += __expf(v2 - pm);
      else { ps = ps*__expf(pm - v2) + 1.0f; pm = v2; }
      int dd = k - j;
      if(dd>=0 && dd<29) atomicAdd(&trd[dd], __expf(tv));  // exp(-1e9c) = 0
    }
  }
  // wave merge of (m,s)
  for(int off=1; off<64; off<<=1){
    float om = __shfl_xor(pm, off);
    float os = __shfl_xor(ps, off);
    if(om > pm){ ps = os + ps*__expf(pm - om); pm = om; }
    else        ps = ps + os*__expf(om - pm);
  }
  if(lane==0){ wm_[wv] = pm; ws_[wv] = ps; }
  __syncthreads();            // also guards trd atomics complete
  if(tid==0){
    float gm = wm_[0], gs = ws_[0];
    for(int i=1;i<5;i++){
      float om = wm_[i], os = ws_[i];
      if(om > gm){ gs = os + gs*__expf(gm - om); gm = om; }
      else        gs = gs + os*__expf(om - gm);
    }
    p_out[bl] = logf(gs) + gm;
  }
  if(tid<29) Lf[bl*30 + tid] = trd[tid];
  if(tid==64){
    float s2 = 0.0f;
    #pragma unroll
    for(int i=0;i<29;i++) s2 += trd[i];
    Lf[bl*30 + 29] = 1.0f - s2;
  }
}

extern "C" void kernel_launch(void* const* d_in, const int* in_sizes, int n_in,
                              void* d_out, int out_size, void* d_ws, size_t ws_size,
                              hipStream_t stream){
  const float* ss = (const float*)d_in[0];
  const float* Q  = (const float*)d_in[1];
  const int*   ls = (const int*)d_in[2];
  float* out = (float*)d_out;
  float* ws  = (float*)d_ws;

  float* cs    = ws;                // 32*8*257  = 65,792
  float* QT    = cs + 65792;        // 8*257*257 = 528,392
  float* alpha = QT + 528392;       // 32*25*257 = 205,600
  float* beta  = alpha + 205600;    // 205,600
  float* Mws   = beta + 205600;     // 32        (total ≈ 4.8 MB)

  float* out_ll = out;              // 205,600
  float* out_M  = out + 205600;     // 32
  float* out_t  = out + 205632;     // 32*24*257*257 = 50,725,632
  float* out_p  = out + 50931264;   // 768
  float* out_Lf = out + 50932032;   // 23,040

  k_cs<<<1, 256, 0, stream>>>(ss, cs);
  k_tq<<<dim3(9,9,8), dim3(32,8), 0, stream>>>(Q, QT);
  k_recur<<<64, 320, 0, stream>>>(Q, QT, cs, ls, alpha, beta);
  k_M<<<1, 64, 0, stream>>>(alpha, ls, Mws, out_M);
  k_ll<<<804, 256, 0, stream>>>(alpha, beta, out_ll);
  k_phase3<<<768, 320, 0, stream>>>(Q, cs, alpha, beta, Mws, out_t, out_p, out_Lf);
}

// Round 10
// 887.723 us; speedup vs baseline: 2.1405x; 2.1405x over previous
//
#include <hip/hip_runtime.h>

#define NEG_ (-1e9f)

__constant__ int d_pat[24] = {0,1,2,1,3,4,2,5,6,7,0,2,1,4,3,5,0,6,2,7,1,3,5,4};

// Faithful np emulation: C = log(ss) fp32; cs = [0, cumsum(C)] sequential fp32.
__global__ void k_cs(const float* __restrict__ ss, float* __restrict__ cs){
  int row = threadIdx.x;          // b*8+s, 0..255 (single block of 256)
  const float* sp = ss + row*256;
  float* cp = cs + row*257;
  cp[0] = 0.0f;
  float acc = 0.0f;
  for(int i=0;i<256;i++){
    acc = acc + logf(sp[i]);      // sequential fp32, matches np.cumsum
    cp[i+1] = acc;
  }
}

// QT[p,k,j] = Q[p,j,k]  (pure copy, no rounding)
__global__ void k_tq(const float* __restrict__ Q, float* __restrict__ QT){
  __shared__ float tile[32][33];
  int p = blockIdx.z;
  int j0 = blockIdx.x*32, k0 = blockIdx.y*32;
  int tx = threadIdx.x, ty = threadIdx.y;
  for(int r=ty; r<32; r+=8){
    int j=j0+r, k=k0+tx;
    if(j<257 && k<257) tile[r][tx] = Q[p*66049 + j*257 + k];
  }
  __syncthreads();
  for(int r=ty; r<32; r+=8){
    int k=k0+r, j=j0+tx;
    if(k<257 && j<257) QT[p*66049 + k*257 + j] = tile[tx][r];
  }
}

// Normalized-scan recursions. blocks 0..31 forward (alpha), 32..63 backward (beta).
// 1024 threads: each output me has P=4 (me<253) or P=3 (me>=253) partial threads
// over contiguous o-chunks; chunk-local online LSE, then in-order merge.
// Counted (-1e9c) lanes are bit-identical to the sequential version (max is
// order-free; log(1)=0); only O(1) normalizers see ~1e-7 reassociation noise.
__global__ __launch_bounds__(1024) void k_recur(
    const float* __restrict__ Q, const float* __restrict__ QT,
    const float* __restrict__ cs, const int* __restrict__ ls,
    float* __restrict__ alpha, float* __restrict__ beta){
  int blk = blockIdx.x;
  bool fwd = (blk < 32);
  int b = fwd ? blk : blk - 32;
  int tid = threadIdx.x;
  int wv = tid >> 6, lane = tid & 63;
  __shared__ float la[257];            // carried normalized state
  __shared__ float csh[2056];
  __shared__ float pmx[1024], psx[1024];
  __shared__ float wredm[16], wrede[16];
  for(int i=tid;i<2056;i+=1024) csh[i] = cs[b*2056 + i];
  // step-invariant work split
  int c, me;
  if(tid >= 771){ c = 3; me = tid - 771; }          // me < 253 here
  else          { c = tid / 257; me = tid - c*257; }
  int P  = (me < 253) ? 4 : 3;
  int lo = (c*257)/P, hi = ((c+1)*257)/P;           // contiguous chunk [lo,hi)
  float ln = 0.0f;                     // n0 = 0 exactly (exp(-1e9)=0)
  if(fwd){
    if(tid<257){
      float v = (tid==0) ? 0.0f : NEG_;
      la[tid] = v;
      alpha[(b*25)*257 + tid] = v;
    }
  } else {
    int lsb = ls[b];
    if(tid<257){
      float v = (tid==lsb) ? 0.0f : NEG_;
      la[tid] = v;
      beta[(b*25+24)*257 + tid] = v;
    }
  }
  __syncthreads();
  for(int step=0; step<24; step++){
    int l = fwd ? step : 23 - step;
    int p = d_pat[l];
    const float* cp = csh + p*257;
    const float* Mx = (fwd ? Q : QT) + p*66049;
    // chunk-local online LSE
    float m = -3.0e38f, s = 0.0f;
    float cme = cp[me];
    for(int o=lo;o<hi;o++){
      float q = Mx[o*257 + me];
      float w;
      if(fwd) w = (o < me) ? ((cme - cp[o]) + q) : NEG_;
      else    w = (me < o) ? ((cp[o] - cme) + q) : NEG_;
      float x = w + la[o];
      if(x <= m) s += __expf(x - m);
      else { s = s*__expf(m - x) + 1.0f; m = x; }
    }
    pmx[tid] = m; psx[tid] = s;
    __syncthreads();                   // partials ready (also guards la reads)
    // in-order merge of this me's P chunks
    float anew = -3.0e38f;
    if(tid < 257){
      int Pm = (tid < 253) ? 4 : 3;
      float mm_ = pmx[tid], ss_ = psx[tid];
      for(int c2=1;c2<Pm;c2++){
        float m2 = pmx[tid + c2*257], s2 = psx[tid + c2*257];
        if(m2 > mm_){ ss_ = s2 + ss_*__expf(mm_ - m2); mm_ = m2; }
        else          ss_ = ss_ + s2*__expf(m2 - mm_);
      }
      anew = logf(ss_) + mm_;          // log(sum)+amax as in scipy
    }
    // block LSE over anew -> normalizer
    float mm = anew;
    for(int off=32; off; off>>=1) mm = fmaxf(mm, __shfl_xor(mm, off));
    if(lane==0) wredm[wv] = mm;
    __syncthreads();
    float gmax = wredm[0];
    for(int i=1;i<16;i++) gmax = fmaxf(gmax, wredm[i]);
    float e = (tid<257) ? __expf(anew - gmax) : 0.0f;
    for(int off=32; off; off>>=1) e += __shfl_xor(e, off);
    if(lane==0) wrede[wv] = e;
    __syncthreads();
    float ssum = wrede[0];
    for(int i=1;i<16;i++) ssum += wrede[i];
    float l2 = logf(ssum) + gmax;
    float nn = ln + l2;                // n = ln + logsumexp(a)
    float d  = ln - nn;                // (ln - n)
    if(tid<257){
      float lan = anew + d;            // carry a + (ln-n)
      la[tid] = lan;
      float st = lan + nn;             // output a + n
      if(fwd) alpha[(b*25 + l+1)*257 + tid] = st;
      else    beta [(b*25 + l  )*257 + tid] = st;
    }
    ln = nn;
    __syncthreads();
  }
}

__global__ void k_M(const float* __restrict__ alpha, const int* __restrict__ ls,
                    float* __restrict__ Mws, float* __restrict__ outM){
  int b = threadIdx.x;
  if(b<32){
    float v = alpha[(b*25+24)*257 + ls[b]];
    Mws[b] = v; outM[b] = v;
  }
}

__global__ void k_ll(const float* __restrict__ alpha, const float* __restrict__ beta,
                     float* __restrict__ out){
  int i = blockIdx.x*256 + threadIdx.x;
  if(i < 32*25*257) out[i] = alpha[i] + beta[i];
}

// one block per (b,l): t (coalesced store), p (online LSE), diagonal traces.
__global__ __launch_bounds__(320) void k_phase3(
    const float* __restrict__ Q, const float* __restrict__ cs,
    const float* __restrict__ alpha, const float* __restrict__ beta,
    const float* __restrict__ Mws,
    float* __restrict__ t_out, float* __restrict__ p_out, float* __restrict__ Lf){
  int bl = blockIdx.x;
  int b = bl/24, l = bl - b*24;
  int pat = d_pat[l];
  int tid = threadIdx.x;
  int wv = tid>>6, lane = tid&63;
  __shared__ float ash[257], bsh[257], cshl[257];
  __shared__ float trd[29];
  __shared__ float wm_[5], ws_[5];
  if(tid<29) trd[tid] = 0.0f;
  for(int i=tid;i<257;i+=320){
    ash[i]  = alpha[(b*25 + l)*257 + i];
    bsh[i]  = beta [(b*25 + l+1)*257 + i];
    cshl[i] = cs[(b*8 + pat)*257 + i];
  }
  float M = Mws[b];
  __syncthreads();
  const float* Qp = Q + pat*66049;
  float* tp = t_out + (long)bl*66049;
  float pm = -3.0e38f, ps = 0.0f;
  if(tid<257){
    int k = tid;
    float bk = bsh[k], ck = cshl[k];
    for(int j=0;j<257;j++){
      float q  = Qp[j*257 + k];
      float w  = (j<k) ? ((ck - cshl[j]) + q) : NEG_;   // fp32(-1e9+q) = -1e9
      float t1 = ash[j] + bk;        // (alpha + beta)
      float t2 = t1 + w;             // ... + W
      float tv = t2 - M;             // ... - M   (left-assoc like numpy)
      tp[j*257 + k] = tv;
      float v2 = tv + w;             // t + W for p
      if(v2 <= pm) ps += __expf(v2 - pm);
      else { ps = ps*__expf(pm - v2) + 1.0f; pm = v2; }
      int dd = k - j;
      if(dd>=0 && dd<29) atomicAdd(&trd[dd], __expf(tv));  // exp(-1e9c) = 0
    }
  }
  // wave merge of (m,s)
  for(int off=1; off<64; off<<=1){
    float om = __shfl_xor(pm, off);
    float os = __shfl_xor(ps, off);
    if(om > pm){ ps = os + ps*__expf(pm - om); pm = om; }
    else        ps = ps + os*__expf(om - pm);
  }
  if(lane==0){ wm_[wv] = pm; ws_[wv] = ps; }
  __syncthreads();            // also guards trd atomics complete
  if(tid==0){
    float gm = wm_[0], gs = ws_[0];
    for(int i=1;i<5;i++){
      float om = wm_[i], os = ws_[i];
      if(om > gm){ gs = os + gs*__expf(gm - om); gm = om; }
      else        gs = gs + os*__expf(om - gm);
    }
    p_out[bl] = logf(gs) + gm;
  }
  if(tid<29) Lf[bl*30 + tid] = trd[tid];
  if(tid==64){
    float s2 = 0.0f;
    #pragma unroll
    for(int i=0;i<29;i++) s2 += trd[i];
    Lf[bl*30 + 29] = 1.0f - s2;
  }
}

extern "C" void kernel_launch(void* const* d_in, const int* in_sizes, int n_in,
                              void* d_out, int out_size, void* d_ws, size_t ws_size,
                              hipStream_t stream){
  const float* ss = (const float*)d_in[0];
  const float* Q  = (const float*)d_in[1];
  const int*   ls = (const int*)d_in[2];
  float* out = (float*)d_out;
  float* ws  = (float*)d_ws;

  float* cs    = ws;                // 32*8*257  = 65,792
  float* QT    = cs + 65792;        // 8*257*257 = 528,392
  float* alpha = QT + 528392;       // 32*25*257 = 205,600
  float* beta  = alpha + 205600;    // 205,600
  float* Mws   = beta + 205600;     // 32        (total ≈ 4.8 MB)

  float* out_ll = out;              // 205,600
  float* out_M  = out + 205600;     // 32
  float* out_t  = out + 205632;     // 32*24*257*257 = 50,725,632
  float* out_p  = out + 50931264;   // 768
  float* out_Lf = out + 50932032;   // 23,040

  k_cs<<<1, 256, 0, stream>>>(ss, cs);
  k_tq<<<dim3(9,9,8), dim3(32,8), 0, stream>>>(Q, QT);
  k_recur<<<64, 1024, 0, stream>>>(Q, QT, cs, ls, alpha, beta);
  k_M<<<1, 64, 0, stream>>>(alpha, ls, Mws, out_M);
  k_ll<<<804, 256, 0, stream>>>(alpha, beta, out_ll);
  k_phase3<<<768, 320, 0, stream>>>(Q, cs, alpha, beta, Mws, out_t, out_p, out_Lf);
}

// Round 12
// 767.270 us; speedup vs baseline: 2.4765x; 1.1570x over previous
//
#include <hip/hip_runtime.h>

#define NEG_ (-1e9f)

__constant__ int d_pat[24] = {0,1,2,1,3,4,2,5,6,7,0,2,1,4,3,5,0,6,2,7,1,3,5,4};

// Faithful np emulation: C = log(ss) fp32; cs = [0, cumsum(C)] sequential fp32.
// LDS-staged so global loads are coalesced; per-row chain order unchanged.
__global__ void k_cs(const float* __restrict__ ss, float* __restrict__ cs){
  __shared__ float tile[256][33];
  int tid = threadIdx.x;            // 0..255, one row per thread
  float acc = 0.0f;
  cs[tid*257] = 0.0f;
  for(int c=0;c<8;c++){
    __syncthreads();
    for(int f=tid; f<8192; f+=256){ // coalesced: 2×128B segments per wave
      int row = f >> 5, ii = f & 31;
      tile[row][ii] = ss[row*256 + c*32 + ii];
    }
    __syncthreads();
    #pragma unroll
    for(int ii=0; ii<32; ii++){
      acc = acc + logf(tile[tid][ii]);   // sequential fp32, matches np.cumsum
      cs[tid*257 + c*32 + ii + 1] = acc;
    }
  }
}

// QT[p,k,j] = Q[p,j,k]  (pure copy, no rounding)
__global__ void k_tq(const float* __restrict__ Q, float* __restrict__ QT){
  __shared__ float tile[32][33];
  int p = blockIdx.z;
  int j0 = blockIdx.x*32, k0 = blockIdx.y*32;
  int tx = threadIdx.x, ty = threadIdx.y;
  for(int r=ty; r<32; r+=8){
    int j=j0+r, k=k0+tx;
    if(j<257 && k<257) tile[r][tx] = Q[p*66049 + j*257 + k];
  }
  __syncthreads();
  for(int r=ty; r<32; r+=8){
    int k=k0+r, j=j0+tx;
    if(k<257 && j<257) QT[p*66049 + k*257 + j] = tile[tx][r];
  }
}

// Normalized-scan recursions. blocks 0..31 forward (alpha), 32..63 backward (beta).
// 1024 threads; each output me has P=4 (me<253) or P=3 partial threads over
// contiguous o-chunks. Chunk processed in software-pipelined batches of 8:
// 8 independent loads -> blocked two-pass LSE -> single merge into running (m,s).
// Cross-count dominance stays exact (exp(±1e9k)=0/replace); O(1) sums see ~1e-7
// reassociation noise (same class as accepted online-LSE deviation).
__global__ __launch_bounds__(1024) void k_recur(
    const float* __restrict__ Q, const float* __restrict__ QT,
    const float* __restrict__ cs, const int* __restrict__ ls,
    float* __restrict__ alpha, float* __restrict__ beta){
  int blk = blockIdx.x;
  bool fwd = (blk < 32);
  int b = fwd ? blk : blk - 32;
  int tid = threadIdx.x;
  int wv = tid >> 6, lane = tid & 63;
  __shared__ float la[257];            // carried normalized state
  __shared__ float csh[2056];
  __shared__ float pmx[1024], psx[1024];
  __shared__ float wredm[16], wrede[16];
  for(int i=tid;i<2056;i+=1024) csh[i] = cs[b*2056 + i];
  // step-invariant work split
  int c, me;
  if(tid >= 771){ c = 3; me = tid - 771; }          // me < 253 here
  else          { c = tid / 257; me = tid - c*257; }
  int P  = (me < 253) ? 4 : 3;
  int lo = (c*257)/P, hi = ((c+1)*257)/P;           // contiguous chunk [lo,hi)
  float ln = 0.0f;                     // n0 = 0 exactly (exp(-1e9)=0)
  if(fwd){
    if(tid<257){
      float v = (tid==0) ? 0.0f : NEG_;
      la[tid] = v;
      alpha[(b*25)*257 + tid] = v;
    }
  } else {
    int lsb = ls[b];
    if(tid<257){
      float v = (tid==lsb) ? 0.0f : NEG_;
      la[tid] = v;
      beta[(b*25+24)*257 + tid] = v;
    }
  }
  __syncthreads();
  for(int step=0; step<24; step++){
    int l = fwd ? step : 23 - step;
    int p = d_pat[l];
    const float* cp = csh + p*257;
    const float* Mx = (fwd ? Q : QT) + p*66049;
    float cme = cp[me];
    float m = -3.0e38f, s = 0.0f;
    int o = lo;
    for(; o+8 <= hi; o += 8){
      float x[8];
      #pragma unroll
      for(int u=0;u<8;u++){
        int oo = o+u;
        float q = Mx[oo*257 + me];     // 8 independent loads, one waitcnt
        float w;
        if(fwd) w = (oo < me) ? ((cme - cp[oo]) + q) : NEG_;
        else    w = (me < oo) ? ((cp[oo] - cme) + q) : NEG_;
        x[u] = w + la[oo];
      }
      float bm = x[0];
      #pragma unroll
      for(int u=1;u<8;u++) bm = fmaxf(bm, x[u]);
      float bs = 0.0f;
      #pragma unroll
      for(int u=0;u<8;u++) bs += __expf(x[u] - bm);  // independent exps
      if(bm <= m) s += bs*__expf(bm - m);
      else { s = s*__expf(m - bm) + bs; m = bm; }
    }
    for(; o<hi; o++){                  // tail, original online update
      float q = Mx[o*257 + me];
      float w;
      if(fwd) w = (o < me) ? ((cme - cp[o]) + q) : NEG_;
      else    w = (me < o) ? ((cp[o] - cme) + q) : NEG_;
      float x = w + la[o];
      if(x <= m) s += __expf(x - m);
      else { s = s*__expf(m - x) + 1.0f; m = x; }
    }
    pmx[tid] = m; psx[tid] = s;
    __syncthreads();                   // partials ready (also guards la reads)
    // in-order merge of this me's P chunks
    float anew = -3.0e38f;
    if(tid < 257){
      int Pm = (tid < 253) ? 4 : 3;
      float mm_ = pmx[tid], ss_ = psx[tid];
      for(int c2=1;c2<Pm;c2++){
        float m2 = pmx[tid + c2*257], s2 = psx[tid + c2*257];
        if(m2 > mm_){ ss_ = s2 + ss_*__expf(mm_ - m2); mm_ = m2; }
        else          ss_ = ss_ + s2*__expf(m2 - mm_);
      }
      anew = logf(ss_) + mm_;          // log(sum)+amax as in scipy
    }
    // block LSE over anew -> normalizer
    float mm = anew;
    for(int off=32; off; off>>=1) mm = fmaxf(mm, __shfl_xor(mm, off));
    if(lane==0) wredm[wv] = mm;
    __syncthreads();
    float gmax = wredm[0];
    for(int i=1;i<16;i++) gmax = fmaxf(gmax, wredm[i]);
    float e = (tid<257) ? __expf(anew - gmax) : 0.0f;
    for(int off=32; off; off>>=1) e += __shfl_xor(e, off);
    if(lane==0) wrede[wv] = e;
    __syncthreads();
    float ssum = wrede[0];
    for(int i=1;i<16;i++) ssum += wrede[i];
    float l2 = logf(ssum) + gmax;
    float nn = ln + l2;                // n = ln + logsumexp(a)
    float d  = ln - nn;                // (ln - n)
    if(tid<257){
      float lan = anew + d;            // carry a + (ln-n)
      la[tid] = lan;
      float st = lan + nn;             // output a + n
      if(fwd) alpha[(b*25 + l+1)*257 + tid] = st;
      else    beta [(b*25 + l  )*257 + tid] = st;
    }
    ln = nn;
    __syncthreads();
  }
}

__global__ void k_M(const float* __restrict__ alpha, const int* __restrict__ ls,
                    float* __restrict__ Mws, float* __restrict__ outM){
  int b = threadIdx.x;
  if(b<32){
    float v = alpha[(b*25+24)*257 + ls[b]];
    Mws[b] = v; outM[b] = v;
  }
}

__global__ void k_ll(const float* __restrict__ alpha, const float* __restrict__ beta,
                     float* __restrict__ out){
  int i = blockIdx.x*256 + threadIdx.x;
  if(i < 32*25*257) out[i] = alpha[i] + beta[i];
}

// one block per (b,l): t (coalesced store), p (online LSE), diagonal traces.
__global__ __launch_bounds__(320) void k_phase3(
    const float* __restrict__ Q, const float* __restrict__ cs,
    const float* __restrict__ alpha, const float* __restrict__ beta,
    const float* __restrict__ Mws,
    float* __restrict__ t_out, float* __restrict__ p_out, float* __restrict__ Lf){
  int bl = blockIdx.x;
  int b = bl/24, l = bl - b*24;
  int pat = d_pat[l];
  int tid = threadIdx.x;
  int wv = tid>>6, lane = tid&63;
  __shared__ float ash[257], bsh[257], cshl[257];
  __shared__ float trd[29];
  __shared__ float wm_[5], ws_[5];
  if(tid<29) trd[tid] = 0.0f;
  for(int i=tid;i<257;i+=320){
    ash[i]  = alpha[(b*25 + l)*257 + i];
    bsh[i]  = beta [(b*25 + l+1)*257 + i];
    cshl[i] = cs[(b*8 + pat)*257 + i];
  }
  float M = Mws[b];
  __syncthreads();
  const float* Qp = Q + pat*66049;
  float* tp = t_out + (long)bl*66049;
  float pm = -3.0e38f, ps = 0.0f;
  if(tid<257){
    int k = tid;
    float bk = bsh[k], ck = cshl[k];
    for(int j=0;j<257;j++){
      float q  = Qp[j*257 + k];
      float w  = (j<k) ? ((ck - cshl[j]) + q) : NEG_;   // fp32(-1e9+q) = -1e9
      float t1 = ash[j] + bk;        // (alpha + beta)
      float t2 = t1 + w;             // ... + W
      float tv = t2 - M;             // ... - M   (left-assoc like numpy)
      tp[j*257 + k] = tv;
      float v2 = tv + w;             // t + W for p
      if(v2 <= pm) ps += __expf(v2 - pm);
      else { ps = ps*__expf(pm - v2) + 1.0f; pm = v2; }
      int dd = k - j;
      if(dd>=0 && dd<29) atomicAdd(&trd[dd], __expf(tv));  // exp(-1e9c) = 0
    }
  }
  // wave merge of (m,s)
  for(int off=1; off<64; off<<=1){
    float om = __shfl_xor(pm, off);
    float os = __shfl_xor(ps, off);
    if(om > pm){ ps = os + ps*__expf(pm - om); pm = om; }
    else        ps = ps + os*__expf(om - pm);
  }
  if(lane==0){ wm_[wv] = pm; ws_[wv] = ps; }
  __syncthreads();            // also guards trd atomics complete
  if(tid==0){
    float gm = wm_[0], gs = ws_[0];
    for(int i=1;i<5;i++){
      float om = wm_[i], os = ws_[i];
      if(om > gm){ gs = os + gs*__expf(gm - om); gm = om; }
      else        gs = gs + os*__expf(om - gm);
    }
    p_out[bl] = logf(gs) + gm;
  }
  if(tid<29) Lf[bl*30 + tid] = trd[tid];
  if(tid==64){
    float s2 = 0.0f;
    #pragma unroll
    for(int i=0;i<29;i++) s2 += trd[i];
    Lf[bl*30 + 29] = 1.0f - s2;
  }
}

extern "C" void kernel_launch(void* const* d_in, const int* in_sizes, int n_in,
                              void* d_out, int out_size, void* d_ws, size_t ws_size,
                              hipStream_t stream){
  const float* ss = (const float*)d_in[0];
  const float* Q  = (const float*)d_in[1];
  const int*   ls = (const int*)d_in[2];
  float* out = (float*)d_out;
  float* ws  = (float*)d_ws;

  float* cs    = ws;                // 32*8*257  = 65,792
  float* QT    = cs + 65792;        // 8*257*257 = 528,392
  float* alpha = QT + 528392;       // 32*25*257 = 205,600
  float* beta  = alpha + 205600;    // 205,600
  float* Mws   = beta + 205600;     // 32        (total ≈ 4.8 MB)

  float* out_ll = out;              // 205,600
  float* out_M  = out + 205600;     // 32
  float* out_t  = out + 205632;     // 32*24*257*257 = 50,725,632
  float* out_p  = out + 50931264;   // 768
  float* out_Lf = out + 50932032;   // 23,040

  k_cs<<<1, 256, 0, stream>>>(ss, cs);
  k_tq<<<dim3(9,9,8), dim3(32,8), 0, stream>>>(Q, QT);
  k_recur<<<64, 1024, 0, stream>>>(Q, QT, cs, ls, alpha, beta);
  k_M<<<1, 64, 0, stream>>>(alpha, ls, Mws, out_M);
  k_ll<<<804, 256, 0, stream>>>(alpha, beta, out_ll);
  k_phase3<<<768, 320, 0, stream>>>(Q, cs, alpha, beta, Mws, out_t, out_p, out_Lf);
}

// Round 15
// 726.646 us; speedup vs baseline: 2.6150x; 1.0559x over previous
//
#include <hip/hip_runtime.h>

#define NEG_ (-1e9f)

__constant__ int d_pat[24] = {0,1,2,1,3,4,2,5,6,7,0,2,1,4,3,5,0,6,2,7,1,3,5,4};

// Faithful np emulation: C = log(ss) fp32; cs = [0, cumsum(C)] sequential fp32.
// LDS-staged so global loads are coalesced; per-row chain order unchanged.
__global__ void k_cs(const float* __restrict__ ss, float* __restrict__ cs){
  __shared__ float tile[256][33];
  int tid = threadIdx.x;            // 0..255, one row per thread
  float acc = 0.0f;
  cs[tid*257] = 0.0f;
  for(int c=0;c<8;c++){
    __syncthreads();
    for(int f=tid; f<8192; f+=256){ // coalesced: 2×128B segments per wave
      int row = f >> 5, ii = f & 31;
      tile[row][ii] = ss[row*256 + c*32 + ii];
    }
    __syncthreads();
    #pragma unroll
    for(int ii=0; ii<32; ii++){
      acc = acc + logf(tile[tid][ii]);   // sequential fp32, matches np.cumsum
      cs[tid*257 + c*32 + ii + 1] = acc;
    }
  }
}

// QT[p,k,j] = Q[p,j,k]  (pure copy, no rounding)
__global__ void k_tq(const float* __restrict__ Q, float* __restrict__ QT){
  __shared__ float tile[32][33];
  int p = blockIdx.z;
  int j0 = blockIdx.x*32, k0 = blockIdx.y*32;
  int tx = threadIdx.x, ty = threadIdx.y;
  for(int r=ty; r<32; r+=8){
    int j=j0+r, k=k0+tx;
    if(j<257 && k<257) tile[r][tx] = Q[p*66049 + j*257 + k];
  }
  __syncthreads();
  for(int r=ty; r<32; r+=8){
    int k=k0+r, j=j0+tx;
    if(k<257 && j<257) QT[p*66049 + k*257 + j] = tile[tx][r];
  }
}

// Batch load: q predicated on the explicit region (NEG lanes issue no request),
// la/cp prefetched from LDS alongside.
#define LOADB(qX,lX,pX,base) { \
  _Pragma("unroll") \
  for(int u=0;u<8;u++){ \
    int oo = (base)+u; \
    bool need = fwd ? (oo < me) : (me < oo); \
    qX[u] = need ? Mx[oo*257 + me] : 0.0f; \
    lX[u] = la[oo]; \
    pX[u] = cp[oo]; \
  } }

// Blocked two-pass LSE over one batch, merged into running (m,s).
// Bit-identical to R12's validated batch path.
#define COMPB(qX,lX,pX,base) { \
  float x[8]; \
  _Pragma("unroll") \
  for(int u=0;u<8;u++){ \
    int oo = (base)+u; \
    float w; \
    if(fwd) w = (oo < me) ? ((cme - pX[u]) + qX[u]) : NEG_; \
    else    w = (me < oo) ? ((pX[u] - cme) + qX[u]) : NEG_; \
    x[u] = w + lX[u]; \
  } \
  float bm = x[0]; \
  _Pragma("unroll") \
  for(int u=1;u<8;u++) bm = fmaxf(bm, x[u]); \
  float bs = 0.0f; \
  _Pragma("unroll") \
  for(int u=0;u<8;u++) bs += __expf(x[u] - bm); \
  if(bm <= m) s += bs*__expf(bm - m); \
  else { s = s*__expf(m - bm) + bs; m = bm; } }

// Normalized-scan recursions. blocks 0..31 forward (alpha), 32..63 backward (beta).
// 1024 threads; each output me has P=4 (me<253) or P=3 partial threads over
// contiguous o-chunks. Chunk processed as double-buffered batches of 8 (A/B named
// register buffers, static indexing): issue next batch's loads before computing
// the current batch -> counted vmcnt, L2 latency hidden under batch math.
__global__ __launch_bounds__(1024) void k_recur(
    const float* __restrict__ Q, const float* __restrict__ QT,
    const float* __restrict__ cs, const int* __restrict__ ls,
    float* __restrict__ alpha, float* __restrict__ beta){
  int blk = blockIdx.x;
  bool fwd = (blk < 32);
  int b = fwd ? blk : blk - 32;
  int tid = threadIdx.x;
  int wv = tid >> 6, lane = tid & 63;
  __shared__ float la[257];            // carried normalized state
  __shared__ float csh[2056];
  __shared__ float pmx[1024], psx[1024];
  __shared__ float wredm[16], wrede[16];
  for(int i=tid;i<2056;i+=1024) csh[i] = cs[b*2056 + i];
  // step-invariant work split
  int c, me;
  if(tid >= 771){ c = 3; me = tid - 771; }          // me < 253 here
  else          { c = tid / 257; me = tid - c*257; }
  int P  = (me < 253) ? 4 : 3;
  int lo = (c*257)/P, hi = ((c+1)*257)/P;           // contiguous chunk [lo,hi)
  float ln = 0.0f;                     // n0 = 0 exactly (exp(-1e9)=0)
  if(fwd){
    if(tid<257){
      float v = (tid==0) ? 0.0f : NEG_;
      la[tid] = v;
      alpha[(b*25)*257 + tid] = v;
    }
  } else {
    int lsb = ls[b];
    if(tid<257){
      float v = (tid==lsb) ? 0.0f : NEG_;
      la[tid] = v;
      beta[(b*25+24)*257 + tid] = v;
    }
  }
  __syncthreads();
  for(int step=0; step<24; step++){
    int l = fwd ? step : 23 - step;
    int p = d_pat[l];
    const float* cp = csh + p*257;
    const float* Mx = (fwd ? Q : QT) + p*66049;
    float cme = cp[me];
    float m = -3.0e38f, s = 0.0f;
    float qA[8], lA[8], pA[8], qB[8], lB[8], pB[8];
    int nb = (hi - lo) >> 3;
    if(nb > 0){ LOADB(qA,lA,pA, lo); }
    for(int bi=0; bi<nb; bi++){
      int obase = lo + bi*8;
      if(bi & 1){
        if(bi+1 < nb){ LOADB(qA,lA,pA, obase+8); }
        COMPB(qB,lB,pB, obase);
      } else {
        if(bi+1 < nb){ LOADB(qB,lB,pB, obase+8); }
        COMPB(qA,lA,pA, obase);
      }
    }
    for(int o = lo + (nb<<3); o<hi; o++){  // tail, original online update
      float q = Mx[o*257 + me];
      float w;
      if(fwd) w = (o < me) ? ((cme - cp[o]) + q) : NEG_;
      else    w = (me < o) ? ((cp[o] - cme) + q) : NEG_;
      float x = w + la[o];
      if(x <= m) s += __expf(x - m);
      else { s = s*__expf(m - x) + 1.0f; m = x; }
    }
    pmx[tid] = m; psx[tid] = s;
    __syncthreads();                   // partials ready (also guards la reads)
    // in-order merge of this me's P chunks
    float anew = -3.0e38f;
    if(tid < 257){
      int Pm = (tid < 253) ? 4 : 3;
      float mm_ = pmx[tid], ss_ = psx[tid];
      for(int c2=1;c2<Pm;c2++){
        float m2 = pmx[tid + c2*257], s2 = psx[tid + c2*257];
        if(m2 > mm_){ ss_ = s2 + ss_*__expf(mm_ - m2); mm_ = m2; }
        else          ss_ = ss_ + s2*__expf(m2 - mm_);
      }
      anew = logf(ss_) + mm_;          // log(sum)+amax as in scipy
    }
    // block LSE over anew -> normalizer
    float mm = anew;
    for(int off=32; off; off>>=1) mm = fmaxf(mm, __shfl_xor(mm, off));
    if(lane==0) wredm[wv] = mm;
    __syncthreads();
    float gmax = wredm[0];
    for(int i=1;i<16;i++) gmax = fmaxf(gmax, wredm[i]);
    float e = (tid<257) ? __expf(anew - gmax) : 0.0f;
    for(int off=32; off; off>>=1) e += __shfl_xor(e, off);
    if(lane==0) wrede[wv] = e;
    __syncthreads();
    float ssum = wrede[0];
    for(int i=1;i<16;i++) ssum += wrede[i];
    float l2 = logf(ssum) + gmax;
    float nn = ln + l2;                // n = ln + logsumexp(a)
    float d  = ln - nn;                // (ln - n)
    if(tid<257){
      float lan = anew + d;            // carry a + (ln-n)
      la[tid] = lan;
      float st = lan + nn;             // output a + n
      if(fwd) alpha[(b*25 + l+1)*257 + tid] = st;
      else    beta [(b*25 + l  )*257 + tid] = st;
    }
    ln = nn;
    __syncthreads();
  }
}

__global__ void k_M(const float* __restrict__ alpha, const int* __restrict__ ls,
                    float* __restrict__ Mws, float* __restrict__ outM){
  int b = threadIdx.x;
  if(b<32){
    float v = alpha[(b*25+24)*257 + ls[b]];
    Mws[b] = v; outM[b] = v;
  }
}

__global__ void k_ll(const float* __restrict__ alpha, const float* __restrict__ beta,
                     float* __restrict__ out){
  int i = blockIdx.x*256 + threadIdx.x;
  if(i < 32*25*257) out[i] = alpha[i] + beta[i];
}

// one block per (b,l): t (coalesced store), p (online LSE), diagonal traces.
__global__ __launch_bounds__(320) void k_phase3(
    const float* __restrict__ Q, const float* __restrict__ cs,
    const float* __restrict__ alpha, const float* __restrict__ beta,
    const float* __restrict__ Mws,
    float* __restrict__ t_out, float* __restrict__ p_out, float* __restrict__ Lf){
  int bl = blockIdx.x;
  int b = bl/24, l = bl - b*24;
  int pat = d_pat[l];
  int tid = threadIdx.x;
  int wv = tid>>6, lane = tid&63;
  __shared__ float ash[257], bsh[257], cshl[257];
  __shared__ float trd[29];
  __shared__ float wm_[5], ws_[5];
  if(tid<29) trd[tid] = 0.0f;
  for(int i=tid;i<257;i+=320){
    ash[i]  = alpha[(b*25 + l)*257 + i];
    bsh[i]  = beta [(b*25 + l+1)*257 + i];
    cshl[i] = cs[(b*8 + pat)*257 + i];
  }
  float M = Mws[b];
  __syncthreads();
  const float* Qp = Q + pat*66049;
  float* tp = t_out + (long)bl*66049;
  float pm = -3.0e38f, ps = 0.0f;
  if(tid<257){
    int k = tid;
    float bk = bsh[k], ck = cshl[k];
    for(int j=0;j<257;j++){
      float q  = Qp[j*257 + k];
      float w  = (j<k) ? ((ck - cshl[j]) + q) : NEG_;   // fp32(-1e9+q) = -1e9
      float t1 = ash[j] + bk;        // (alpha + beta)
      float t2 = t1 + w;             // ... + W
      float tv = t2 - M;             // ... - M   (left-assoc like numpy)
      tp[j*257 + k] = tv;
      float v2 = tv + w;             // t + W for p
      if(v2 <= pm) ps += __expf(v2 - pm);
      else { ps = ps*__expf(pm - v2) + 1.0f; pm = v2; }
      int dd = k - j;
      if(dd>=0 && dd<29) atomicAdd(&trd[dd], __expf(tv));  // exp(-1e9c) = 0
    }
  }
  // wave merge of (m,s)
  for(int off=1; off<64; off<<=1){
    float om = __shfl_xor(pm, off);
    float os = __shfl_xor(ps, off);
    if(om > pm){ ps = os + ps*__expf(pm - om); pm = om; }
    else        ps = ps + os*__expf(om - pm);
  }
  if(lane==0){ wm_[wv] = pm; ws_[wv] = ps; }
  __syncthreads();            // also guards trd atomics complete
  if(tid==0){
    float gm = wm_[0], gs = ws_[0];
    for(int i=1;i<5;i++){
      float om = wm_[i], os = ws_[i];
      if(om > gm){ gs = os + gs*__expf(gm - om); gm = om; }
      else        gs = gs + os*__expf(om - gm);
    }
    p_out[bl] = logf(gs) + gm;
  }
  if(tid<29) Lf[bl*30 + tid] = trd[tid];
  if(tid==64){
    float s2 = 0.0f;
    #pragma unroll
    for(int i=0;i<29;i++) s2 += trd[i];
    Lf[bl*30 + 29] = 1.0f - s2;
  }
}

extern "C" void kernel_launch(void* const* d_in, const int* in_sizes, int n_in,
                              void* d_out, int out_size, void* d_ws, size_t ws_size,
                              hipStream_t stream){
  const float* ss = (const float*)d_in[0];
  const float* Q  = (const float*)d_in[1];
  const int*   ls = (const int*)d_in[2];
  float* out = (float*)d_out;
  float* ws  = (float*)d_ws;

  float* cs    = ws;                // 32*8*257  = 65,792
  float* QT    = cs + 65792;        // 8*257*257 = 528,392
  float* alpha = QT + 528392;       // 32*25*257 = 205,600
  float* beta  = alpha + 205600;    // 205,600
  float* Mws   = beta + 205600;     // 32        (total ≈ 4.8 MB)

  float* out_ll = out;              // 205,600
  float* out_M  = out + 205600;     // 32
  float* out_t  = out + 205632;     // 32*24*257*257 = 50,725,632
  float* out_p  = out + 50931264;   // 768
  float* out_Lf = out + 50932032;   // 23,040

  k_cs<<<1, 256, 0, stream>>>(ss, cs);
  k_tq<<<dim3(9,9,8), dim3(32,8), 0, stream>>>(Q, QT);
  k_recur<<<64, 1024, 0, stream>>>(Q, QT, cs, ls, alpha, beta);
  k_M<<<1, 64, 0, stream>>>(alpha, ls, Mws, out_M);
  k_ll<<<804, 256, 0, stream>>>(alpha, beta, out_ll);
  k_phase3<<<768, 320, 0, stream>>>(Q, cs, alpha, beta, Mws, out_t, out_p, out_Lf);
}